// Round 10
// baseline (3250.629 us; speedup 1.0000x reference)
//
#include <hip/hip_runtime.h>

// VQ bottleneck: h [4,4096,1024] f32, codebook [8192,1024] f32, mask [4,4096] i32
// out = [ z_q (16384*1024) | indices-as-f32 (16384) | commit_loss | codebook_loss ]
//
// Decision is f32-FAITHFUL to the reference formula (dist = (h2+c2) - 2*dot in f32,
// first-index tie-break). Round-9 lesson: an exact-f64 rescan MISMATCHES the np ref
// on f32-tie rows -> the ref inherits f32 quantization; replicate it, don't beat it.
//
// Scratch (inside d_out, consumed before k_output overwrites the z_q region):
//   pairs (float2 per (row,tile)) -> d_out[0 .. 8MB)
//   c2/h2 -> d_out + 32MB (float offset 8M)
//   lacc  -> losses slot (8B double), read before overwrite

static constexpr int M  = 16384;   // B*T
static constexpr int Dv = 1024;    // D
static constexpr int KC = 8192;    // codebook size
static constexpr int BM = 128, BN = 128, BK = 32;
static constexpr int NT = KC / BN; // 64 n-tiles

#define AS_STRIDE (BM + 4)   // 132 floats
// bswz max = 127 + 4*(127>>5) = 139 -> stride >= 140 (Round-8 bug: 136 overflowed into
// Bs[k+1][0..3], racing with cols 0..3 staging -> corrupt distances for cols {0..3,124..127})
#define BS_STRIDE (BM + 12)  // 140 floats; 140 % 4 == 0 keeps float4 row alignment

__device__ __forceinline__ int bswz(int col) { return col + ((col >> 5) << 2); }

// strictly smaller, or equal with smaller index (numpy argmin first-occurrence rule)
__device__ __forceinline__ bool dbetter(float da, int ia, float db, int ib) {
  return (da < db) || (da == db && ia < ib);
}

// ---------------- kernel 1: row sum-of-squares for codebook and h ----------------
__global__ __launch_bounds__(256) void k_sumsq(const float* __restrict__ cb,
                                               const float* __restrict__ h,
                                               float* __restrict__ c2,
                                               float* __restrict__ h2) {
  int row = blockIdx.x;
  const float* src;
  float* dst;
  if (row < KC) { src = cb + (size_t)row * Dv; dst = c2 + row; }
  else          { src = h  + (size_t)(row - KC) * Dv; dst = h2 + (row - KC); }
  int t = threadIdx.x;
  float4 v = reinterpret_cast<const float4*>(src)[t];
  float s = v.x * v.x + v.y * v.y + v.z * v.z + v.w * v.w;
  #pragma unroll
  for (int o = 32; o >= 1; o >>= 1) s += __shfl_down(s, o);
  __shared__ float red[4];
  int wid = t >> 6, lane = t & 63;
  if (lane == 0) red[wid] = s;
  __syncthreads();
  if (t == 0) *dst = red[0] + red[1] + red[2] + red[3];
}

// ---------------- kernel 2: fused fp32 GEMM + per-(row, tile) argmin ----------------
__global__ __launch_bounds__(256, 3)
void k_dist_argmin(const float* __restrict__ h, const float* __restrict__ cb,
                   const float* __restrict__ c2, const float* __restrict__ h2,
                   float2* __restrict__ pairs) {
  __shared__ __align__(16) float As[BK][AS_STRIDE];
  __shared__ __align__(16) float Bs[BK][BS_STRIDE];

  const int R0 = blockIdx.x * BM;
  const int C0 = blockIdx.y * BN;
  const int tid = threadIdx.x;
  const int tx = tid & 15, ty = tid >> 4;

  float acc[8][8];
  #pragma unroll
  for (int i = 0; i < 8; ++i)
    #pragma unroll
    for (int j = 0; j < 8; ++j) acc[i][j] = 0.0f;

  for (int k0 = 0; k0 < Dv; k0 += BK) {
    #pragma unroll
    for (int i = 0; i < 4; ++i) {
      int f = tid + i * 256;          // 0..1023 float4 slots
      int row = f >> 3;               // 0..127
      int kf = f & 7;                 // float4 index along K
      float4 va = *reinterpret_cast<const float4*>(
          h + (size_t)(R0 + row) * Dv + (k0 + (kf << 2)));
      As[(kf << 2) + 0][row] = va.x;
      As[(kf << 2) + 1][row] = va.y;
      As[(kf << 2) + 2][row] = va.z;
      As[(kf << 2) + 3][row] = va.w;
      float4 vb = *reinterpret_cast<const float4*>(
          cb + (size_t)(C0 + row) * Dv + (k0 + (kf << 2)));
      int wc = bswz(row);             // 0..139, in-bounds with BS_STRIDE=140
      Bs[(kf << 2) + 0][wc] = vb.x;
      Bs[(kf << 2) + 1][wc] = vb.y;
      Bs[(kf << 2) + 2][wc] = vb.z;
      Bs[(kf << 2) + 3][wc] = vb.w;
    }
    __syncthreads();
    const int bc = bswz(tx << 3);
    #pragma unroll 4
    for (int kk = 0; kk < BK; ++kk) {
      float a[8], b[8];
      *reinterpret_cast<float4*>(&a[0]) = *reinterpret_cast<const float4*>(&As[kk][ty << 3]);
      *reinterpret_cast<float4*>(&a[4]) = *reinterpret_cast<const float4*>(&As[kk][(ty << 3) + 4]);
      *reinterpret_cast<float4*>(&b[0]) = *reinterpret_cast<const float4*>(&Bs[kk][bc]);
      *reinterpret_cast<float4*>(&b[4]) = *reinterpret_cast<const float4*>(&Bs[kk][bc + 4]);
      #pragma unroll
      for (int i = 0; i < 8; ++i)
        #pragma unroll
        for (int j = 0; j < 8; ++j) acc[i][j] = fmaf(a[i], b[j], acc[i][j]);
    }
    __syncthreads();
  }

  // epilogue: dist = (h2 + c2) - 2*dot in f32, per-row argmin over this tile's 128 cands
  #pragma unroll
  for (int i = 0; i < 8; ++i) {
    int r = R0 + (ty << 3) + i;
    float hv = h2[r];
    float best = 3.402823466e38f;
    int bidx = 0x7fffffff;
    #pragma unroll
    for (int j = 0; j < 8; ++j) {
      int c = C0 + (tx << 3) + j;
      float dist = (hv + c2[c]) - 2.0f * acc[i][j];
      if (dbetter(dist, c, best, bidx)) { best = dist; bidx = c; }
    }
    #pragma unroll
    for (int o = 1; o < 16; o <<= 1) {
      float ov = __shfl_xor(best, o, 16);
      int oi   = __shfl_xor(bidx, o, 16);
      if (dbetter(ov, oi, best, bidx)) { best = ov; bidx = oi; }
    }
    if (tx == 0) pairs[(size_t)r * NT + blockIdx.y] = make_float2(best, __int_as_float(bidx));
  }
}

// ------- kernel 3: merge 64 tile minima per row -> indices output (as float) -------
__global__ __launch_bounds__(256) void k_argmin_final(const float2* __restrict__ pairs,
                                                      float* __restrict__ idxf_out) {
  int row = blockIdx.x * 4 + (threadIdx.x >> 6);
  int lane = threadIdx.x & 63;
  float2 p = pairs[(size_t)row * NT + lane];
  float v = p.x;
  int idx = __float_as_int(p.y);
  #pragma unroll
  for (int o = 1; o < 64; o <<= 1) {
    float ov = __shfl_xor(v, o);
    int oi   = __shfl_xor(idx, o);
    if (dbetter(ov, oi, v, idx)) { v = ov; idx = oi; }
  }
  if (lane == 0) idxf_out[row] = (float)idx;
}

// ---------------- kernel 4: gather z, write z_q, accumulate masked loss ----------------
__global__ __launch_bounds__(256) void k_output(const float* __restrict__ h,
                                                const float* __restrict__ cb,
                                                const float* __restrict__ idxf,
                                                const int* __restrict__ mask,
                                                float* __restrict__ zq,
                                                double* __restrict__ lacc) {
  int row = blockIdx.x;
  int t = threadIdx.x;
  int ci = (int)idxf[row];             // exact: idx < 8192
  float4 hv = reinterpret_cast<const float4*>(h + (size_t)row * Dv)[t];
  float4 cv = reinterpret_cast<const float4*>(cb + (size_t)ci * Dv)[t];
  float4 o;
  o.x = hv.x + (cv.x - hv.x);  // replicate reference op order: h + (z - h)
  o.y = hv.y + (cv.y - hv.y);
  o.z = hv.z + (cv.z - hv.z);
  o.w = hv.w + (cv.w - hv.w);
  reinterpret_cast<float4*>(zq + (size_t)row * Dv)[t] = o;

  float dx = hv.x - cv.x, dy = hv.y - cv.y, dz = hv.z - cv.z, dw = hv.w - cv.w;
  float s = dx * dx + dy * dy + dz * dz + dw * dw;
  #pragma unroll
  for (int o2 = 32; o2 >= 1; o2 >>= 1) s += __shfl_down(s, o2);
  __shared__ float red[4];
  int wid = t >> 6, lane = t & 63;
  if (lane == 0) red[wid] = s;
  __syncthreads();
  if (t == 0 && mask[row] != 0)
    atomicAdd(lacc, (double)(red[0] + red[1] + red[2] + red[3]));
}

// ---------------- kernel 5: finalize losses ----------------
__global__ __launch_bounds__(256) void k_finalize(const int* __restrict__ mask,
                                                  const double* __restrict__ lacc,
                                                  float* __restrict__ losses) {
  int t = threadIdx.x;
  int cnt = 0;
  for (int i = t; i < M; i += 256) cnt += mask[i];
  #pragma unroll
  for (int o = 32; o >= 1; o >>= 1) cnt += __shfl_down(cnt, o);
  __shared__ int red[4];
  int wid = t >> 6, lane = t & 63;
  if (lane == 0) red[wid] = cnt;
  __syncthreads();
  if (t == 0) {
    int total = red[0] + red[1] + red[2] + red[3];
    double denom = (double)total * 1024.0 + 1e-8;
    double acc = *lacc;                // read BEFORE overwriting the slot
    float l = (float)(acc / denom);
    losses[0] = l;   // commit_loss
    losses[1] = l;   // codebook_loss (same forward value)
  }
}

extern "C" void kernel_launch(void* const* d_in, const int* in_sizes, int n_in,
                              void* d_out, int out_size, void* d_ws, size_t ws_size,
                              hipStream_t stream) {
  const float* h   = (const float*)d_in[0];
  const float* cb  = (const float*)d_in[1];
  const int* mask  = (const int*)d_in[2];
  float* out = (float*)d_out;

  float* zq     = out;                          // [M*Dv]
  float* idxf   = out + (size_t)M * Dv;         // [M]
  float* losses = idxf + M;                     // [2]

  // scratch inside d_out (all consumed before k_output overwrites z_q region)
  float2* pairs = (float2*)out;                         // [M*NT] float2 = 8 MB
  float*  c2    = out + (size_t)8 * 1024 * 1024;        // 8192 f32 @ 32 MB
  float*  h2    = c2 + KC;                              // 16384 f32
  double* lacc  = (double*)losses;                      // 8 bytes, 8B-aligned

  hipMemsetAsync(lacc, 0, sizeof(double), stream);
  k_sumsq<<<KC + M, 256, 0, stream>>>(cb, h, c2, h2);
  dim3 g2(M / BM, KC / BN);
  k_dist_argmin<<<g2, 256, 0, stream>>>(h, cb, c2, h2, pairs);
  k_argmin_final<<<M / 4, 256, 0, stream>>>(pairs, idxf);
  k_output<<<M, 256, 0, stream>>>(h, cb, idxf, mask, zq, lacc);
  k_finalize<<<1, 256, 0, stream>>>(mask, lacc, losses);
}

// Round 12
// 1440.624 us; speedup vs baseline: 2.2564x; 2.2564x over previous
//
#include <hip/hip_runtime.h>

// VQ bottleneck: h [4,4096,1024] f32, codebook [8192,1024] f32, mask [4,4096] i32
// out = [ z_q (16384*1024) | indices-as-f32 (16384) | commit_loss | codebook_loss ]
//
// Strategy: bf16-MFMA GEMM computes APPROX distances -> per-(row, 64-col group) min.
// Rescan flags groups within EPS of the row min and recomputes those cands with the
// EXACT Round-10-passing f32 semantics (sequential ascending fmaf chain, (h2+c2)-2dot,
// first-index tie-break) -> indices bit-identical to the proven-passing kernel.
//
// d_out scratch (float offsets into the 16M-float z_q region; all consumed before
// k_output overwrites it):  gmin [0,2M) | hb bf16 [2M,10M) | cbb bf16 [10M,14M)
//                           c2 [14M,+8192) | h2 [+8192,+24576)
// lacc aliases the losses slot (read before overwrite). d_ws unused.

typedef __attribute__((ext_vector_type(8))) short short8;   // 8 bf16 (4 VGPRs)
typedef __attribute__((ext_vector_type(4))) float f32x4;    // 4 f32 acc

static constexpr int M  = 16384;
static constexpr int Dv = 1024;
static constexpr int KC = 8192;
static constexpr int BM = 128, BN = 128, BK = 64;
static constexpr int NG = 128;          // 64-col groups
#define EPS_FLAG 0.10f                  // >> 2x bf16 approx error bound (~0.06)

__device__ __forceinline__ unsigned short bf16rne(float f) {
  unsigned u = __float_as_uint(f);
  return (unsigned short)((u + 0x7FFFu + ((u >> 16) & 1u)) >> 16);
}

// ---------------- kernel 0: f32 -> bf16 conversion (h and cb) ----------------
__global__ __launch_bounds__(256) void k_tobf16(const float* __restrict__ h,
                                                const float* __restrict__ cb,
                                                unsigned short* __restrict__ hb,
                                                unsigned short* __restrict__ cbb) {
  const long nh = (long)M * Dv;
  const long total4 = (nh + (long)KC * Dv) >> 2;
  for (long i = (long)blockIdx.x * 256 + threadIdx.x; i < total4;
       i += (long)gridDim.x * 256) {
    long e = i << 2;
    const float* src; unsigned short* dst;
    if (e < nh) { src = h + e;        dst = hb + e; }
    else        { src = cb + (e - nh); dst = cbb + (e - nh); }
    float4 v = *(const float4*)src;
    ushort4 o;
    o.x = bf16rne(v.x); o.y = bf16rne(v.y); o.z = bf16rne(v.z); o.w = bf16rne(v.w);
    *(ushort4*)dst = o;
  }
}

// ---------------- kernel 1: row sum-of-squares (unchanged, proven) ----------------
__global__ __launch_bounds__(256) void k_sumsq(const float* __restrict__ cb,
                                               const float* __restrict__ h,
                                               float* __restrict__ c2,
                                               float* __restrict__ h2) {
  int row = blockIdx.x;
  const float* src; float* dst;
  if (row < KC) { src = cb + (size_t)row * Dv; dst = c2 + row; }
  else          { src = h  + (size_t)(row - KC) * Dv; dst = h2 + (row - KC); }
  int t = threadIdx.x;
  float4 v = reinterpret_cast<const float4*>(src)[t];
  float s = v.x * v.x + v.y * v.y + v.z * v.z + v.w * v.w;
  #pragma unroll
  for (int o = 32; o >= 1; o >>= 1) s += __shfl_down(s, o);
  __shared__ float red[4];
  int wid = t >> 6, lane = t & 63;
  if (lane == 0) red[wid] = s;
  __syncthreads();
  if (t == 0) *dst = red[0] + red[1] + red[2] + red[3];
}

// -------- kernel 2: bf16 MFMA GEMM -> per-(row, 64-col group) approx dist min --------
__global__ __launch_bounds__(256)
void k_gemm_min(const unsigned short* __restrict__ hb,
                const unsigned short* __restrict__ cbb,
                const float* __restrict__ c2, const float* __restrict__ h2,
                float* __restrict__ gmin) {   // gmin[M][NG]
  __shared__ __align__(16) char Ab[BM * BK * 2];   // 16 KB, XOR-swizzled
  __shared__ __align__(16) char Bb[BN * BK * 2];   // 16 KB

  const int tid = threadIdx.x;
  const int R0 = blockIdx.y * BM;
  const int C0 = blockIdx.x * BN;
  const int w = tid >> 6, lane = tid & 63;
  const int wr = w >> 1, wc = w & 1;          // wave quadrant (rows, cols)
  const int l15 = lane & 15, grp = lane >> 4;

  f32x4 acc[4][4];
  #pragma unroll
  for (int i = 0; i < 4; ++i)
    #pragma unroll
    for (int j = 0; j < 4; ++j) acc[i][j] = (f32x4){0.f, 0.f, 0.f, 0.f};

  for (int k0 = 0; k0 < Dv; k0 += BK) {
    // stage 128x64 bf16 tiles; 16B chunks; swizzle byte ^= (row&7)<<4
    #pragma unroll
    for (int i = 0; i < 4; ++i) {
      int id = tid + i * 256;                 // 0..1023
      int row = id >> 3, kc = id & 7;
      int off = (row * 128 + kc * 16) ^ ((row & 7) << 4);
      uint4 va = *(const uint4*)(hb + (size_t)(R0 + row) * Dv + k0 + kc * 8);
      *(uint4*)(Ab + off) = va;
      uint4 vb = *(const uint4*)(cbb + (size_t)(C0 + row) * Dv + k0 + kc * 8);
      *(uint4*)(Bb + off) = vb;
    }
    __syncthreads();
    #pragma unroll
    for (int ks = 0; ks < 2; ++ks) {          // two K=32 substeps
      short8 af[4], bf[4];
      #pragma unroll
      for (int f = 0; f < 4; ++f) {
        int rowA = wr * 64 + f * 16 + l15;
        af[f] = *(const short8*)(Ab + ((rowA * 128 + ks * 64 + grp * 16) ^ ((rowA & 7) << 4)));
        int rowB = wc * 64 + f * 16 + l15;
        bf[f] = *(const short8*)(Bb + ((rowB * 128 + ks * 64 + grp * 16) ^ ((rowB & 7) << 4)));
      }
      #pragma unroll
      for (int fi = 0; fi < 4; ++fi)
        #pragma unroll
        for (int fj = 0; fj < 4; ++fj)
          acc[fi][fj] = __builtin_amdgcn_mfma_f32_16x16x32_bf16(af[fi], bf[fj],
                                                               acc[fi][fj], 0, 0, 0);
    }
    __syncthreads();
  }

  // epilogue: dist = (h2+c2) - 2*dot ; per-row min over this wave's 64 cols
  // C/D layout: col = l15, row = grp*4 + reg  [HW-verified, m89]
  float c2v[4];
  #pragma unroll
  for (int fj = 0; fj < 4; ++fj) c2v[fj] = c2[C0 + wc * 64 + fj * 16 + l15];
  const int gidx = blockIdx.x * 2 + wc;
  #pragma unroll
  for (int fi = 0; fi < 4; ++fi) {
    #pragma unroll
    for (int reg = 0; reg < 4; ++reg) {
      int r = R0 + wr * 64 + fi * 16 + grp * 4 + reg;
      float hv = h2[r];
      float dmin = 3.402823466e38f;
      #pragma unroll
      for (int fj = 0; fj < 4; ++fj)
        dmin = fminf(dmin, (hv + c2v[fj]) - 2.0f * acc[fi][fj][reg]);
      #pragma unroll
      for (int o = 1; o < 16; o <<= 1) dmin = fminf(dmin, __shfl_xor(dmin, o, 16));
      if (l15 == 0) gmin[(size_t)r * NG + gidx] = dmin;
    }
  }
}

// -------- kernel 3: exact f32 rescan of flagged groups (Round-10 semantics) --------
__global__ __launch_bounds__(64)
void k_rescan(const float* __restrict__ h, const float* __restrict__ cb,
              const float* __restrict__ c2, const float* __restrict__ h2,
              const float* __restrict__ gmin, float* __restrict__ idxf) {
  __shared__ float hrow[Dv];
  __shared__ int tl[NG];
  __shared__ int nf;
  const int row = blockIdx.x, t = threadIdx.x;
  #pragma unroll
  for (int i = 0; i < 16; ++i) hrow[t + i * 64] = h[(size_t)row * Dv + t + i * 64];
  if (t == 0) nf = 0;
  __syncthreads();

  float g0 = gmin[(size_t)row * NG + t];
  float g1 = gmin[(size_t)row * NG + 64 + t];
  float gm = fminf(g0, g1);
  #pragma unroll
  for (int o = 1; o < 64; o <<= 1) gm = fminf(gm, __shfl_xor(gm, o));
  if (g0 <= gm + EPS_FLAG) { int p = atomicAdd(&nf, 1); tl[p] = t; }
  if (g1 <= gm + EPS_FLAG) { int p = atomicAdd(&nf, 1); tl[p] = 64 + t; }
  __syncthreads();

  float bd = 3.402823466e38f; int bi = 0x7fffffff;
  const float hv = h2[row];
  const int n = nf;
  for (int fi = 0; fi < n; ++fi) {            // unordered list OK: tie-break on global idx
    int c = tl[fi] * 64 + t;
    const float* crow = cb + (size_t)c * Dv;
    float acc = 0.f;
    for (int k = 0; k < Dv; ++k) acc = fmaf(hrow[k], crow[k], acc);  // sequential = R10 order
    float dist = (hv + c2[c]) - 2.0f * acc;
    if (dist < bd || (dist == bd && c < bi)) { bd = dist; bi = c; }
  }
  #pragma unroll
  for (int o = 1; o < 64; o <<= 1) {
    float od = __shfl_xor(bd, o); int oi = __shfl_xor(bi, o);
    if (od < bd || (od == bd && oi < bi)) { bd = od; bi = oi; }
  }
  if (t == 0) idxf[row] = (float)bi;
}

// ---------------- kernel 4: gather z, write z_q, accumulate masked loss ----------------
__global__ __launch_bounds__(256) void k_output(const float* __restrict__ h,
                                                const float* __restrict__ cb,
                                                const float* __restrict__ idxf,
                                                const int* __restrict__ mask,
                                                float* __restrict__ zq,
                                                double* __restrict__ lacc) {
  int row = blockIdx.x;
  int t = threadIdx.x;
  int ci = (int)idxf[row];
  float4 hv = reinterpret_cast<const float4*>(h + (size_t)row * Dv)[t];
  float4 cv = reinterpret_cast<const float4*>(cb + (size_t)ci * Dv)[t];
  float4 o;
  o.x = hv.x + (cv.x - hv.x);
  o.y = hv.y + (cv.y - hv.y);
  o.z = hv.z + (cv.z - hv.z);
  o.w = hv.w + (cv.w - hv.w);
  reinterpret_cast<float4*>(zq + (size_t)row * Dv)[t] = o;

  float dx = hv.x - cv.x, dy = hv.y - cv.y, dz = hv.z - cv.z, dw = hv.w - cv.w;
  float s = dx * dx + dy * dy + dz * dz + dw * dw;
  #pragma unroll
  for (int o2 = 32; o2 >= 1; o2 >>= 1) s += __shfl_down(s, o2);
  __shared__ float red[4];
  int wid = t >> 6, lane = t & 63;
  if (lane == 0) red[wid] = s;
  __syncthreads();
  if (t == 0 && mask[row] != 0)
    atomicAdd(lacc, (double)(red[0] + red[1] + red[2] + red[3]));
}

// ---------------- kernel 5: finalize losses ----------------
__global__ __launch_bounds__(256) void k_finalize(const int* __restrict__ mask,
                                                  const double* __restrict__ lacc,
                                                  float* __restrict__ losses) {
  int t = threadIdx.x;
  int cnt = 0;
  for (int i = t; i < M; i += 256) cnt += mask[i];
  #pragma unroll
  for (int o = 32; o >= 1; o >>= 1) cnt += __shfl_down(cnt, o);
  __shared__ int red[4];
  int wid = t >> 6, lane = t & 63;
  if (lane == 0) red[wid] = cnt;
  __syncthreads();
  if (t == 0) {
    int total = red[0] + red[1] + red[2] + red[3];
    double denom = (double)total * 1024.0 + 1e-8;
    double acc = *lacc;
    float l = (float)(acc / denom);
    losses[0] = l;
    losses[1] = l;
  }
}

extern "C" void kernel_launch(void* const* d_in, const int* in_sizes, int n_in,
                              void* d_out, int out_size, void* d_ws, size_t ws_size,
                              hipStream_t stream) {
  const float* h   = (const float*)d_in[0];
  const float* cb  = (const float*)d_in[1];
  const int* mask  = (const int*)d_in[2];
  float* out = (float*)d_out;

  float* zq     = out;                              // [M*Dv]
  float* idxf   = out + (size_t)M * Dv;             // [M]
  float* losses = idxf + M;                         // [2]

  // scratch inside d_out's z_q region (float offsets)
  float*          gmin = out;                                   // [M*NG] = 2M floats
  unsigned short* hb   = (unsigned short*)(out + (size_t)2 * 1024 * 1024);   // 16M bf16
  unsigned short* cbb  = (unsigned short*)(out + (size_t)10 * 1024 * 1024);  // 8M bf16
  float*          c2   = out + (size_t)14 * 1024 * 1024;        // 8192
  float*          h2   = c2 + KC;                               // 16384
  double*         lacc = (double*)losses;

  hipMemsetAsync(lacc, 0, sizeof(double), stream);
  k_tobf16<<<2048, 256, 0, stream>>>(h, cb, hb, cbb);
  k_sumsq<<<KC + M, 256, 0, stream>>>(cb, h, c2, h2);
  dim3 gg(KC / BN, M / BM);   // x = col tile (64), y = row tile (128)
  k_gemm_min<<<gg, 256, 0, stream>>>(hb, cbb, c2, h2, gmin);
  k_rescan<<<M, 64, 0, stream>>>(h, cb, c2, h2, gmin, idxf);
  k_output<<<M, 256, 0, stream>>>(h, cb, idxf, mask, zq, lacc);
  k_finalize<<<1, 256, 0, stream>>>(mask, lacc, losses);
}